// Round 9
// baseline (253.021 us; speedup 1.0000x reference)
//
#include <hip/hip_runtime.h>

typedef unsigned long long u64;
typedef unsigned int u32;
typedef float nfloat4 __attribute__((ext_vector_type(4)));   // for nontemporal builtin

static constexpr int NF = 17;      // features per point
static constexpr int BCOL = 9;     // beta column
static constexpr int CCOL = 14;    // first ccoord column (17-3)
static constexpr int CONDCAP = 256;
static constexpr int REFCAP = 256;
static constexpr int CANDCAP = 6144;  // candidates per event (expect ~4.6k at TAU0=0.93)
static constexpr int RPB = 512;    // rows per block in k_filter
static constexpr int FT = 1024;    // k_resolve threads
static constexpr int TT = 256;     // k_killfin threads
static constexpr int BPE = 64;     // kill blocks per event (64*256*KB2 = 65536 = P)
static constexpr int KB2 = 4;      // kill batch depth
static constexpr int FCAP = 1536;  // killfin LDS survivor capacity (30 KB)

#define T_B_F  ((float)0.2)        // matches numpy float32(0.2)
#define R2_F   ((float)(0.7*0.7))  // matches numpy float32 semantics
#define TAU0_F ((float)0.93)       // candidate threshold (correctness independent of it)

__device__ __forceinline__ u64 kmax(u64 a, u64 b){ return a > b ? a : b; }

__device__ __forceinline__ u64 shfl_down_u64(u64 v, int off){
    u32 lo = (u32)v, hi = (u32)(v >> 32);
    lo = __shfl_down(lo, off, 64);
    hi = __shfl_down(hi, off, 64);
    return ((u64)hi << 32) | lo;
}

__device__ __forceinline__ u64 shfl_u64(u64 v, int lane){
    u32 lo = (u32)v, hi = (u32)(v >> 32);
    lo = __shfl(lo, lane, 64);
    hi = __shfl(hi, lane, 64);
    return ((u64)hi << 32) | lo;
}

__device__ __forceinline__ u64 waveReduceMax(u64 k){
    #pragma unroll
    for (int off = 32; off > 0; off >>= 1){
        u64 o = shfl_down_u64(k, off);
        if (o > k) k = o;
    }
    return k;
}

__device__ __forceinline__ void waveReduceMaxPair(u64 &k, int &p){
    #pragma unroll
    for (int off = 32; off > 0; off >>= 1){
        u64 ok = shfl_down_u64(k, off);
        int op = __shfl_down(p, off, 64);
        if (ok > k){ k = ok; p = op; }
    }
}

// distance with NO fp contraction — must match numpy (mul,mul,mul,add,add)
__device__ __forceinline__ float dist2(float cx, float cy, float cz,
                                       float rx, float ry, float rz){
    #pragma clang fp contract(off)
    float dx = cx - rx, dy = cy - ry, dz = cz - rz;
    float sx = dx * dx, sy = dy * dy, sz = dz * dz;
    return (sx + sy) + sz;
}

__device__ __forceinline__ u64 makeKey(float beta, u32 idx){
    return ((u64)__float_as_uint(beta) << 32) | (u64)(0xFFFFFFFFu - idx);
}

// ---------------- kernel 0: zero control block (4 KB) ----------------
__global__ void k_init(u32* ws){
    int t = threadIdx.x;
    if (t < 1024) ws[t] = 0;
}

// ---------------- kernel 1: filter + candidate push + zero dout ---------------
// All global STORES happen after the last __syncthreads() (fire-and-forget):
// s_barrier on gfx950 drains vmcnt(0), so stores before a barrier stall the
// block until 35 KB of zero-fill lands. Stores last -> barrier waits loads only.
__global__ __launch_bounds__(512) void k_filter(
    const float4* __restrict__ x4, float4* __restrict__ out4,
    int* __restrict__ cnt0, float4* __restrict__ cA, int* __restrict__ iA,
    int* __restrict__ candCnt, float4* __restrict__ candC, int* __restrict__ candI,
    int P, int chunksPerEvent)
{
    __shared__ float lds[RPB * NF];           // 34816 B
    __shared__ int swc[8], swb[8], sbase;
    __shared__ int swc2[8], swb2[8], sbase2;

    int e = blockIdx.x / chunksPerEvent;
    int chunk = blockIdx.x % chunksPerEvent;
    int rowStart = chunk * RPB;
    size_t tile4 = (size_t)blockIdx.x * (RPB * NF / 4);   // 2176 float4 per tile

    float4* lds4 = (float4*)lds;
    const int N4 = RPB * NF / 4;
    for (int i = threadIdx.x; i < N4; i += 512)
        lds4[i] = x4[tile4 + i];              // pure loads before the barrier
    __syncthreads();

    int tid = threadIdx.x, lid = tid & 63, wid = tid >> 6;
    float be = lds[tid*NF+BCOL];
    float cx = lds[tid*NF+CCOL], cy = lds[tid*NF+CCOL+1], cz = lds[tid*NF+CCOL+2];
    bool kp = (be >= T_B_F);
    bool cd = (be >= TAU0_F);
    u64 bal  = __ballot(kp);
    u64 bal2 = __ballot(cd);
    if (lid == 0){ swc[wid] = __popcll(bal); swc2[wid] = __popcll(bal2); }
    __syncthreads();
    if (tid == 0){
        int tot = 0, tot2 = 0;
        for (int w = 0; w < 8; w++){
            swb[w] = tot;  tot  += swc[w];
            swb2[w] = tot2; tot2 += swc2[w];
        }
        sbase  = tot  ? atomicAdd(&cnt0[e], tot)     : 0;   // 1 returning atomic / block
        sbase2 = tot2 ? atomicAdd(&candCnt[e], tot2) : 0;
    }
    __syncthreads();
    // ---- all global stores below; no barrier follows ----
    u64 lm = (1ull << lid) - 1;
    if (kp){
        int pos = sbase + swb[wid] + __popcll(bal & lm);
        size_t eoff = (size_t)e * P;
        cA[eoff + pos] = make_float4(cx, cy, cz, be);
        iA[eoff + pos] = rowStart + tid;
    }
    if (cd){
        int pos = sbase2 + swb2[wid] + __popcll(bal2 & lm);
        if (pos < CANDCAP){
            candC[(size_t)e * CANDCAP + pos] = make_float4(cx, cy, cz, be);
            candI[(size_t)e * CANDCAP + pos] = rowStart + tid;
        }
    }
    nfloat4 z = (nfloat4)0.f;
    for (int i = tid; i < N4; i += 512)
        __builtin_nontemporal_store(z, (nfloat4*)&out4[tile4 + i]);
}

// ---------------- kernel 2: per-event exact greedy MIS over candidates --------
// Kills among candidates come only from higher-key candidates, so greedy over
// the candidate list is exact for refs with beta >= TAU0. Payload comes
// pre-gathered from k_filter (contiguous stream, no x gather).
__global__ __launch_bounds__(1024) void k_resolve(
    const float4* __restrict__ candC, const int* __restrict__ candI,
    const int* __restrict__ candCnt, int* __restrict__ nrefs,
    int* __restrict__ condlist, float* __restrict__ refXg,
    float* __restrict__ refYg, float* __restrict__ refZg)
{
    __shared__ u64 skey[CANDCAP];                           // 49152 B
    __shared__ float sx[CANDCAP], sy[CANDCAP], sz[CANDCAP]; // 73728 B
    __shared__ u64 wk[16]; __shared__ int wp[16];
    __shared__ float rfx[REFCAP], rfy[REFCAP], rfz[REFCAP];
    __shared__ int rci[REFCAP];
    __shared__ int snr;

    int e = blockIdx.x;
    int tid = threadIdx.x, lid = tid & 63, wid = tid >> 6;
    int m = candCnt[e];
    if (m > CANDCAP || m == 0){ if (tid == 0) nrefs[e] = 0; return; }  // overflow -> fallback

    u64 bk = 0; int bp = 0;
    for (int i = tid; i < m; i += FT){
        float4 c = candC[(size_t)e * CANDCAP + i];
        u64 k = makeKey(c.w, (u32)candI[(size_t)e * CANDCAP + i]);
        skey[i] = k;
        sx[i] = c.x; sy[i] = c.y; sz[i] = c.z;
        if (k > bk){ bk = k; bp = i; }
    }
    waveReduceMaxPair(bk, bp);
    if (lid == 0){ wk[wid] = bk; wp[wid] = bp; }
    __syncthreads();

    if (wid == 0){
        u64 key = (lid < 16) ? wk[lid] : 0;
        int mp  = (lid < 16) ? wp[lid] : 0;
        waveReduceMaxPair(key, mp);
        key = shfl_u64(key, 0); mp = __shfl(mp, 0, 64);

        int n = m, nr = 0;
        while (key){
            if (nr == REFCAP) break;
            float rx = sx[mp], ry = sy[mp], rz = sz[mp];
            if (lid == 0){
                rfx[nr] = rx; rfy[nr] = ry; rfz[nr] = rz;
                rci[nr] = (int)(0xFFFFFFFFu - (u32)key);
            }
            nr++;
            u64 nk = 0; int np = -1; int alive = 0;
            for (int i0 = 0; i0 < n; i0 += 64){
                int i = i0 + lid;
                bool inb = i < n;
                int ii = inb ? i : 0;
                u64 k2 = skey[ii];
                float xx = sx[ii], yy = sy[ii], zz = sz[ii];
                bool keep = inb && !(dist2(xx, yy, zz, rx, ry, rz) <= R2_F);
                u64 b = __ballot(keep);
                if (keep){
                    int pos = alive + __popcll(b & ((1ull << lid) - 1));
                    skey[pos] = k2; sx[pos] = xx; sy[pos] = yy; sz[pos] = zz;
                    if (k2 > nk){ nk = k2; np = pos; }
                }
                alive += __popcll(b);
            }
            waveReduceMaxPair(nk, np);
            key = shfl_u64(nk, 0); mp = __shfl(np, 0, 64);
            n = alive;
        }
        if (lid == 0) snr = nr;
    }
    __syncthreads();
    int nr = snr;
    for (int i = tid; i < nr; i += FT){
        refXg[e*REFCAP + i] = rfx[i];
        refYg[e*REFCAP + i] = rfy[i];
        refZg[e*REFCAP + i] = rfz[i];
        condlist[e*CONDCAP + i] = rci[i];
    }
    if (tid == 0) nrefs[e] = nr;
}

// ---------------- kernel 3: kill pass + fused per-event finish ---------------
// All BPE blocks of an event kill+compact survivors to cB/iB; the LAST block
// (doneE handshake: fence -> atomicAdd -> fence) runs the finish: LDS-resident
// single-wave greedy on survivors (global-round fallback if > FCAP), then the
// epilogue (condensate-row scatter + row_splits by globally-last event).
__global__ __launch_bounds__(256) void k_killfin(
    const float* __restrict__ x,
    float4* cA, int* iA, float4* cB, int* iB,
    const int* __restrict__ cnt0, int* __restrict__ cnt1,
    u64* __restrict__ argmax1, const int* __restrict__ nrefs,
    const float* __restrict__ refXg, const float* __restrict__ refYg,
    const float* __restrict__ refZg,
    int* __restrict__ ncond, const int* __restrict__ condlistG,
    int* __restrict__ doneE, int* __restrict__ done,
    float* __restrict__ out, int P, int E)
{
    __shared__ float rfx[REFCAP], rfy[REFCAP], rfz[REFCAP];   // 3 KB
    __shared__ int swc[4], swb[4], sbase;
    __shared__ u64 sred[4];
    __shared__ u64 fkey[FCAP];                                // 12 KB
    __shared__ float fx[FCAP], fy[FCAP], fz[FCAP];            // 18 KB
    __shared__ int condL[CONDCAP];                            // 1 KB
    __shared__ int scnt, snc, slast;
    __shared__ u64 skeyb;
    __shared__ float srefc[3];

    int e = blockIdx.x / BPE;
    int c = blockIdx.x % BPE;
    int tid = threadIdx.x, lid = tid & 63, wid = tid >> 6;
    int n = cnt0[e];
    int nr = nrefs[e];
    size_t eoff = (size_t)e * P;

    if (c * TT < n){                          // block-uniform guard
        for (int i = tid; i < nr; i += TT){
            rfx[i] = refXg[e*REFCAP + i];
            rfy[i] = refYg[e*REFCAP + i];
            rfz[i] = refZg[e*REFCAP + i];
        }
        __syncthreads();
        int stride = BPE * TT;
        float4 cc[KB2]; int ixv[KB2]; bool kp[KB2]; u64 bal[KB2];
        int wcnt = 0; u64 lk = 0;
        #pragma unroll
        for (int k = 0; k < KB2; k++){
            int i = c * TT + tid + k * stride;
            bool inb = i < n;
            int ii = inb ? i : 0;
            cc[k] = cA[eoff + ii]; ixv[k] = iA[eoff + ii];
            bool alive = inb;
            for (int r = 0; r < nr; r++)
                if (alive && dist2(cc[k].x, cc[k].y, cc[k].z, rfx[r], rfy[r], rfz[r]) <= R2_F)
                    alive = false;
            kp[k] = alive;
            bal[k] = __ballot(alive);
            wcnt += __popcll(bal[k]);
            if (alive) lk = kmax(lk, makeKey(cc[k].w, (u32)ixv[k]));
        }
        u64 kw = waveReduceMax(lk);
        if (lid == 0){ swc[wid] = wcnt; sred[wid] = kw; }
        __syncthreads();
        if (tid == 0){
            int tot = 0;
            for (int w = 0; w < 4; w++){ swb[w] = tot; tot += swc[w]; }
            sbase = tot ? atomicAdd(&cnt1[e], tot) : 0;
            u64 mm = kmax(kmax(sred[0], sred[1]), kmax(sred[2], sred[3]));
            if (mm) atomicMax(&argmax1[e], mm);
        }
        __syncthreads();
        int pos = sbase + swb[wid];
        u64 lm = (1ull << lid) - 1;
        #pragma unroll
        for (int k = 0; k < KB2; k++){
            if (kp[k]){
                int p_ = pos + __popcll(bal[k] & lm);
                cB[eoff + p_] = cc[k]; iB[eoff + p_] = ixv[k];
            }
            pos += __popcll(bal[k]);
        }
    }
    __threadfence();                           // release survivor writes
    if (tid == 0) slast = (atomicAdd(&doneE[e], 1) == BPE - 1) ? 1 : 0;
    __syncthreads();
    if (!slast) return;
    __threadfence();                           // acquire other blocks' writes

    // ---------- finish (last block of this event) ----------
    int n1 = atomicAdd(&cnt1[e], 0);
    u64 key = atomicMax(&argmax1[e], 0ull);
    for (int i = tid; i < nr; i += TT) condL[i] = condlistG[e*CONDCAP + i];
    if (tid == 0) snc = nr;
    __syncthreads();

    float4* cIn = cB + eoff; int* iIn = iB + eoff;
    float4* cOut = cA + eoff; int* iOut = iA + eoff;

    // fallback global rounds while survivors exceed LDS (whp never)
    while (n1 > FCAP){
        float betaRef = __uint_as_float((u32)(key >> 32));
        if (!(betaRef >= T_B_F)) break;
        u32 refIdx = 0xFFFFFFFFu - (u32)key;
        if (tid == 0){
            if (snc < CONDCAP) condL[snc] = (int)refIdx;
            snc++;
            size_t rb = (eoff + refIdx) * NF;
            srefc[0] = x[rb + CCOL]; srefc[1] = x[rb + CCOL + 1]; srefc[2] = x[rb + CCOL + 2];
            scnt = 0;
        }
        __syncthreads();
        float rx = srefc[0], ry = srefc[1], rz = srefc[2];
        u64 localKey = 0;
        for (int i = tid; i < n1; i += TT){
            float4 cc = cIn[i]; int idx = iIn[i];
            bool keep = !(dist2(cc.x, cc.y, cc.z, rx, ry, rz) <= R2_F);
            u64 b = __ballot(keep);
            int cw = __popcll(b);
            int b_ = 0;
            if (lid == 0) b_ = cw ? atomicAdd(&scnt, cw) : 0;
            b_ = __shfl(b_, 0, 64);
            if (keep){
                int pos = b_ + __popcll(b & ((1ull << lid) - 1));
                cOut[pos] = cc; iOut[pos] = idx;
                localKey = kmax(localKey, makeKey(cc.w, (u32)idx));
            }
        }
        u64 kw2 = waveReduceMax(localKey);
        if (lid == 0) sred[wid] = kw2;
        __syncthreads();
        if (tid == 0) skeyb = kmax(kmax(sred[0], sred[1]), kmax(sred[2], sred[3]));
        __syncthreads();
        key = skeyb; n1 = scnt;
        { float4* t = cIn; cIn = cOut; cOut = t; }
        { int* t = iIn; iIn = iOut; iOut = t; }
        __syncthreads();
    }

    // LDS-resident single-wave rounds
    float b0 = __uint_as_float((u32)(key >> 32));
    if (b0 >= T_B_F && n1 > 0){
        for (int i = tid; i < n1; i += TT){
            float4 cc = cIn[i]; int idx = iIn[i];
            fkey[i] = makeKey(cc.w, (u32)idx);
            fx[i] = cc.x; fy[i] = cc.y; fz[i] = cc.z;
        }
        __syncthreads();
        if (wid == 0){
            int snc_l = snc;
            int mp = -1;
            int nn = n1;
            while (true){
                float betaRef = __uint_as_float((u32)(key >> 32));
                if (!(betaRef >= T_B_F)) break;
                u32 refIdx = 0xFFFFFFFFu - (u32)key;
                if (lid == 0 && snc_l < CONDCAP) condL[snc_l] = (int)refIdx;
                snc_l++;
                float rx, ry, rz;
                if (mp >= 0){ rx = fx[mp]; ry = fy[mp]; rz = fz[mp]; }
                else {
                    size_t rb = (eoff + refIdx) * NF;
                    rx = x[rb + CCOL]; ry = x[rb + CCOL + 1]; rz = x[rb + CCOL + 2];
                }
                u64 bk = 0; int bp = -1; int alive = 0;
                for (int i0 = 0; i0 < nn; i0 += 64){
                    int i = i0 + lid;
                    bool inb = i < nn;
                    int ii = inb ? i : 0;
                    u64 k = fkey[ii];
                    float xx = fx[ii], yy = fy[ii], zz = fz[ii];
                    bool keep = inb && !(dist2(xx, yy, zz, rx, ry, rz) <= R2_F);
                    u64 b = __ballot(keep);
                    if (keep){
                        int pos = alive + __popcll(b & ((1ull << lid) - 1));
                        fkey[pos] = k; fx[pos] = xx; fy[pos] = yy; fz[pos] = zz;
                        if (k > bk){ bk = k; bp = pos; }
                    }
                    alive += __popcll(b);
                }
                waveReduceMaxPair(bk, bp);
                key = shfl_u64(bk, 0);
                mp = __shfl(bp, 0, 64);
                nn = alive;
            }
            if (lid == 0) snc = snc_l;
        }
    }
    __syncthreads();

    // ---- epilogue: scatter condensate rows + row_splits (globally last) ----
    int ncT = snc;
    int ncc = ncT > CONDCAP ? CONDCAP : ncT;
    for (int i = tid; i < ncc * NF; i += TT){
        int j = i / NF, f = i - j * NF;
        int row = condL[j];
        size_t base = (eoff + row) * NF;
        out[base + f] = x[base + f];
    }
    if (tid == 0){
        ncond[e] = ncT;
        __threadfence();
        int r = atomicAdd(done, 1);
        if (r == E - 1){
            size_t ob = (size_t)E * P * NF;
            int s = 0;
            out[ob] = 0.0f;
            for (int i = 0; i < E; i++){
                s += atomicAdd(&ncond[i], 0);
                out[ob + i + 1] = (float)s;
            }
        }
    }
}

extern "C" void kernel_launch(void* const* d_in, const int* in_sizes, int n_in,
                              void* d_out, int out_size, void* d_ws, size_t ws_size,
                              hipStream_t stream) {
    const float* x = (const float*)d_in[0];
    int N = in_sizes[0] / NF;
    int E = in_sizes[1] - 1;
    int P = N / E;
    float* out = (float*)d_out;
    char* ws = (char*)d_ws;

    // ws layout (first 4 KB zeroed by k_init)
    u64* argmax1 = (u64*)ws;                        // [E]
    int* cnt0    = (int*)(ws + 1024);               // [E]
    int* cnt1    = (int*)(ws + 1280);               // [E]
    int* candCnt = (int*)(ws + 1536);               // [E]
    int* nrefs   = (int*)(ws + 1792);               // [E]
    int* ncond   = (int*)(ws + 2048);               // [E]
    int* doneE   = (int*)(ws + 2304);               // [E]
    int* done    = (int*)(ws + 2560);               // [1]
    int* condlist= (int*)(ws + 4096);               // [E][CONDCAP] 16 KB
    float* refXg = (float*)(ws + 20480);            // [E][REFCAP]  16 KB each
    float* refYg = (float*)(ws + 36864);
    float* refZg = (float*)(ws + 53248);
    float4* candC = (float4*)(ws + 69632);          // [E][CANDCAP] float4 = 1.5 MB
    int* candI    = (int*)(ws + 69632 + (size_t)16 * CANDCAP * 16);   // 384 KB
    size_t listOff = 4194304;                       // 4 MB, clear of cand arrays
    size_t listElems = (size_t)E * P;
    float4* cA = (float4*)(ws + listOff);
    float4* cB = (float4*)(ws + listOff + listElems * 16);
    int* iA = (int*)(ws + listOff + listElems * 32);
    int* iB = (int*)(ws + listOff + listElems * 36);

    k_init<<<1, 1024, 0, stream>>>((u32*)ws);

    int chunksPerEvent = P / RPB;                   // 128
    k_filter<<<E * chunksPerEvent, 512, 0, stream>>>(
        (const float4*)x, (float4*)out, cnt0, cA, iA, candCnt, candC, candI,
        P, chunksPerEvent);

    k_resolve<<<E, 1024, 0, stream>>>(
        candC, candI, candCnt, nrefs, condlist, refXg, refYg, refZg);

    k_killfin<<<E * BPE, 256, 0, stream>>>(
        x, cA, iA, cB, iB, cnt0, cnt1, argmax1, nrefs, refXg, refYg, refZg,
        ncond, condlist, doneE, done, out, P, E);
}

// Round 10
// 195.553 us; speedup vs baseline: 1.2939x; 1.2939x over previous
//
#include <hip/hip_runtime.h>

typedef unsigned long long u64;
typedef unsigned int u32;
typedef float nfloat4 __attribute__((ext_vector_type(4)));   // for nontemporal builtin

static constexpr int NF = 17;      // features per point
static constexpr int BCOL = 9;     // beta column
static constexpr int CCOL = 14;    // first ccoord column (17-3)
static constexpr int CONDCAP = 256;
static constexpr int REFCAP = 256;
static constexpr int CANDCAP = 6144;  // candidates per event (expect ~4.6k at TAU0=0.93)
static constexpr int RPB = 512;    // rows per block in k_filter
static constexpr int FT = 1024;    // k_resolve / k_finish2 threads
static constexpr int KB = 8;       // streaming batch depth (MLP)
static constexpr int LCAP = 7168;  // k_finish2 LDS capacity (143 KB)

#define T_B_F  ((float)0.2)        // matches numpy float32(0.2)
#define R2_F   ((float)(0.7*0.7))  // matches numpy float32 semantics
#define TAU0_F ((float)0.93)       // candidate threshold (correctness independent of it)

__device__ __forceinline__ u64 kmax(u64 a, u64 b){ return a > b ? a : b; }

__device__ __forceinline__ u64 shfl_down_u64(u64 v, int off){
    u32 lo = (u32)v, hi = (u32)(v >> 32);
    lo = __shfl_down(lo, off, 64);
    hi = __shfl_down(hi, off, 64);
    return ((u64)hi << 32) | lo;
}

__device__ __forceinline__ u64 shfl_u64(u64 v, int lane){
    u32 lo = (u32)v, hi = (u32)(v >> 32);
    lo = __shfl(lo, lane, 64);
    hi = __shfl(hi, lane, 64);
    return ((u64)hi << 32) | lo;
}

__device__ __forceinline__ u64 waveReduceMax(u64 k){
    #pragma unroll
    for (int off = 32; off > 0; off >>= 1){
        u64 o = shfl_down_u64(k, off);
        if (o > k) k = o;
    }
    return k;
}

__device__ __forceinline__ void waveReduceMaxPair(u64 &k, int &p){
    #pragma unroll
    for (int off = 32; off > 0; off >>= 1){
        u64 ok = shfl_down_u64(k, off);
        int op = __shfl_down(p, off, 64);
        if (ok > k){ k = ok; p = op; }
    }
}

// distance with NO fp contraction — must match numpy (mul,mul,mul,add,add)
__device__ __forceinline__ float dist2(float cx, float cy, float cz,
                                       float rx, float ry, float rz){
    #pragma clang fp contract(off)
    float dx = cx - rx, dy = cy - ry, dz = cz - rz;
    float sx = dx * dx, sy = dy * dy, sz = dz * dz;
    return (sx + sy) + sz;
}

__device__ __forceinline__ u64 makeKey(float beta, u32 idx){
    return ((u64)__float_as_uint(beta) << 32) | (u64)(0xFFFFFFFFu - idx);
}

// ---------------- kernel 0: zero control block (4 KB) ----------------
__global__ void k_init(u32* ws){
    int t = threadIdx.x;
    if (t < 1024) ws[t] = 0;
}

// ---------------- kernel 1: filter + candidate push + zero dout ---------------
// All global STORES happen after the last __syncthreads() (fire-and-forget):
// s_barrier on gfx950 drains vmcnt(0), so stores before a barrier stall the
// block until 35 KB of zero-fill lands. Stores last -> barrier waits loads only.
__global__ __launch_bounds__(512) void k_filter(
    const float4* __restrict__ x4, float4* __restrict__ out4,
    int* __restrict__ cnt0, float4* __restrict__ cA, int* __restrict__ iA,
    int* __restrict__ candCnt, float4* __restrict__ candC, int* __restrict__ candI,
    int P, int chunksPerEvent)
{
    __shared__ float lds[RPB * NF];           // 34816 B
    __shared__ int swc[8], swb[8], sbase;
    __shared__ int swc2[8], swb2[8], sbase2;

    int e = blockIdx.x / chunksPerEvent;
    int chunk = blockIdx.x % chunksPerEvent;
    int rowStart = chunk * RPB;
    size_t tile4 = (size_t)blockIdx.x * (RPB * NF / 4);   // 2176 float4 per tile

    float4* lds4 = (float4*)lds;
    const int N4 = RPB * NF / 4;
    for (int i = threadIdx.x; i < N4; i += 512)
        lds4[i] = x4[tile4 + i];              // pure loads before the barrier
    __syncthreads();

    int tid = threadIdx.x, lid = tid & 63, wid = tid >> 6;
    float be = lds[tid*NF+BCOL];
    float cx = lds[tid*NF+CCOL], cy = lds[tid*NF+CCOL+1], cz = lds[tid*NF+CCOL+2];
    bool kp = (be >= T_B_F);
    bool cd = (be >= TAU0_F);
    u64 bal  = __ballot(kp);
    u64 bal2 = __ballot(cd);
    if (lid == 0){ swc[wid] = __popcll(bal); swc2[wid] = __popcll(bal2); }
    __syncthreads();
    if (tid == 0){
        int tot = 0, tot2 = 0;
        for (int w = 0; w < 8; w++){
            swb[w] = tot;  tot  += swc[w];
            swb2[w] = tot2; tot2 += swc2[w];
        }
        sbase  = tot  ? atomicAdd(&cnt0[e], tot)     : 0;   // 1 returning atomic / block
        sbase2 = tot2 ? atomicAdd(&candCnt[e], tot2) : 0;
    }
    __syncthreads();
    // ---- all global stores below; no barrier follows ----
    u64 lm = (1ull << lid) - 1;
    if (kp){
        int pos = sbase + swb[wid] + __popcll(bal & lm);
        size_t eoff = (size_t)e * P;
        cA[eoff + pos] = make_float4(cx, cy, cz, be);
        iA[eoff + pos] = rowStart + tid;
    }
    if (cd){
        int pos = sbase2 + swb2[wid] + __popcll(bal2 & lm);
        if (pos < CANDCAP){
            candC[(size_t)e * CANDCAP + pos] = make_float4(cx, cy, cz, be);
            candI[(size_t)e * CANDCAP + pos] = rowStart + tid;
        }
    }
    nfloat4 z = (nfloat4)0.f;
    for (int i = tid; i < N4; i += 512)
        __builtin_nontemporal_store(z, (nfloat4*)&out4[tile4 + i]);
}

// ---------------- kernel 2: per-event exact greedy MIS over candidates --------
// Kills among candidates come only from higher-key candidates, so greedy over
// the candidate list is exact for refs with beta >= TAU0. Payload pre-gathered
// by k_filter (contiguous stream, no x gather). Single-wave fused
// kill+compact+argmax rounds in LDS, no barriers in the loop.
__global__ __launch_bounds__(1024) void k_resolve(
    const float4* __restrict__ candC, const int* __restrict__ candI,
    const int* __restrict__ candCnt, int* __restrict__ nrefs,
    int* __restrict__ condlist, float* __restrict__ refXg,
    float* __restrict__ refYg, float* __restrict__ refZg)
{
    __shared__ u64 skey[CANDCAP];                           // 49152 B
    __shared__ float sx[CANDCAP], sy[CANDCAP], sz[CANDCAP]; // 73728 B
    __shared__ u64 wk[16]; __shared__ int wp[16];
    __shared__ float rfx[REFCAP], rfy[REFCAP], rfz[REFCAP];
    __shared__ int rci[REFCAP];
    __shared__ int snr;

    int e = blockIdx.x;
    int tid = threadIdx.x, lid = tid & 63, wid = tid >> 6;
    int m = candCnt[e];
    if (m > CANDCAP || m == 0){ if (tid == 0) nrefs[e] = 0; return; }  // overflow -> fallback

    u64 bk = 0; int bp = 0;
    for (int i = tid; i < m; i += FT){
        float4 c = candC[(size_t)e * CANDCAP + i];
        u64 k = makeKey(c.w, (u32)candI[(size_t)e * CANDCAP + i]);
        skey[i] = k;
        sx[i] = c.x; sy[i] = c.y; sz[i] = c.z;
        if (k > bk){ bk = k; bp = i; }
    }
    waveReduceMaxPair(bk, bp);
    if (lid == 0){ wk[wid] = bk; wp[wid] = bp; }
    __syncthreads();

    if (wid == 0){
        u64 key = (lid < 16) ? wk[lid] : 0;
        int mp  = (lid < 16) ? wp[lid] : 0;
        waveReduceMaxPair(key, mp);
        key = shfl_u64(key, 0); mp = __shfl(mp, 0, 64);

        int n = m, nr = 0;
        while (key){
            if (nr == REFCAP) break;            // fallback resolves the rest exactly
            float rx = sx[mp], ry = sy[mp], rz = sz[mp];
            if (lid == 0){
                rfx[nr] = rx; rfy[nr] = ry; rfz[nr] = rz;
                rci[nr] = (int)(0xFFFFFFFFu - (u32)key);
            }
            nr++;
            u64 nk = 0; int np = -1; int alive = 0;
            for (int i0 = 0; i0 < n; i0 += 64){
                int i = i0 + lid;
                bool inb = i < n;
                int ii = inb ? i : 0;
                u64 k2 = skey[ii];
                float xx = sx[ii], yy = sy[ii], zz = sz[ii];
                bool keep = inb && !(dist2(xx, yy, zz, rx, ry, rz) <= R2_F);
                u64 b = __ballot(keep);
                if (keep){
                    int pos = alive + __popcll(b & ((1ull << lid) - 1));
                    skey[pos] = k2; sx[pos] = xx; sy[pos] = yy; sz[pos] = zz;
                    if (k2 > nk){ nk = k2; np = pos; }
                }
                alive += __popcll(b);
            }
            waveReduceMaxPair(nk, np);
            key = shfl_u64(nk, 0); mp = __shfl(np, 0, 64);
            n = alive;
        }
        if (lid == 0) snr = nr;
    }
    __syncthreads();
    int nr = snr;
    for (int i = tid; i < nr; i += FT){
        refXg[e*REFCAP + i] = rfx[i];
        refYg[e*REFCAP + i] = rfy[i];
        refZg[e*REFCAP + i] = rfz[i];
        condlist[e*CONDCAP + i] = rci[i];
    }
    if (tid == 0) nrefs[e] = nr;
}

// ---------------- kernel 3: full-grid kill pass vs all resolved refs ----------
// Survivors (> r from every ref) are compacted to cB/iB; whp there are few.
__global__ __launch_bounds__(256) void k_kill(
    const float4* __restrict__ cA, const int* __restrict__ iA,
    float4* __restrict__ cB, int* __restrict__ iB,
    const int* __restrict__ cnt0, int* __restrict__ cnt1,
    u64* __restrict__ argmax1, const int* __restrict__ nrefs,
    const float* __restrict__ refXg, const float* __restrict__ refYg,
    const float* __restrict__ refZg, int P, int bpe)
{
    __shared__ float rfx[REFCAP], rfy[REFCAP], rfz[REFCAP];
    __shared__ int swc[4], swb[4], sbase;
    __shared__ u64 sred[4];

    int e = blockIdx.x / bpe;
    int c = blockIdx.x % bpe;
    int n = cnt0[e];
    if (c * 256 >= n) return;                  // uniform early-out
    int nr = nrefs[e];
    for (int i = threadIdx.x; i < nr; i += 256){
        rfx[i] = refXg[e*REFCAP + i];
        rfy[i] = refYg[e*REFCAP + i];
        rfz[i] = refZg[e*REFCAP + i];
    }
    __syncthreads();

    int tid = threadIdx.x, lid = tid & 63, wid = tid >> 6;
    size_t eoff = (size_t)e * P;
    int stride = bpe * 256;

    float4 cc[KB]; int ixv[KB]; bool kp[KB]; u64 bal[KB];
    int wcnt = 0; u64 lk = 0;
    #pragma unroll
    for (int k = 0; k < KB; k++){
        int i = c * 256 + tid + k * stride;
        bool inb = i < n;
        int ii = inb ? i : 0;
        cc[k] = cA[eoff + ii]; ixv[k] = iA[eoff + ii];
        bool alive = inb;
        for (int r = 0; r < nr; r++){
            if (alive && dist2(cc[k].x, cc[k].y, cc[k].z, rfx[r], rfy[r], rfz[r]) <= R2_F)
                alive = false;
        }
        kp[k] = alive;
        bal[k] = __ballot(alive);
        wcnt += __popcll(bal[k]);
        if (alive) lk = kmax(lk, makeKey(cc[k].w, (u32)ixv[k]));
    }
    u64 kw = waveReduceMax(lk);
    if (lid == 0){ swc[wid] = wcnt; sred[wid] = kw; }
    __syncthreads();
    if (tid == 0){
        int tot = 0;
        for (int w = 0; w < 4; w++){ swb[w] = tot; tot += swc[w]; }
        sbase = tot ? atomicAdd(&cnt1[e], tot) : 0;
        u64 mm = kmax(kmax(sred[0], sred[1]), kmax(sred[2], sred[3]));
        if (mm) atomicMax(&argmax1[e], mm);
    }
    __syncthreads();
    int pos = sbase + swb[wid];
    u64 lm = (1ull << lid) - 1;
    #pragma unroll
    for (int k = 0; k < KB; k++){
        if (kp[k]){
            int p_ = pos + __popcll(bal[k] & lm);
            cB[eoff + p_] = cc[k]; iB[eoff + p_] = ixv[k];
        }
        pos += __popcll(bal[k]);
    }
}

// ---------------- kernel 4: finish greedy on survivors (usually tiny) ---------
// Phase 1: global rounds while n > LCAP (whp never). Phase 2: single-wave
// LDS-resident fused rounds. Epilogue: scatter + row_splits.
__global__ __launch_bounds__(1024) void k_finish2(
    const float* __restrict__ x,
    float4* cB, int* iB, float4* cA, int* iA,
    const u64* __restrict__ argmax1, const int* __restrict__ cnt1,
    const int* __restrict__ nrefs, int* __restrict__ ncond,
    const int* __restrict__ condlistG, int* __restrict__ done,
    float* __restrict__ out, int P, int E)
{
    __shared__ u64 skey[LCAP];                       // 57344 B
    __shared__ float sx[LCAP], sy[LCAP], sz[LCAP];   // 86016 B
    __shared__ u64 sred[16];
    __shared__ int condL[CONDCAP];
    __shared__ int scnt, snc;
    __shared__ u64 skeyb;
    __shared__ float srefc[3];

    int e = blockIdx.x;
    int tid = threadIdx.x, lid = tid & 63, wid = tid >> 6;
    int n = cnt1[e];
    u64 key = argmax1[e];
    float4* cIn = cB + (size_t)e * P; int* iIn = iB + (size_t)e * P;
    float4* cOut = cA + (size_t)e * P; int* iOut = iA + (size_t)e * P;

    int nr0 = nrefs[e];
    for (int i = tid; i < nr0; i += FT) condL[i] = condlistG[e*CONDCAP + i];
    if (tid == 0) snc = nr0;
    __syncthreads();

    // ---- phase 1: global-memory rounds while list too big for LDS (whp never)
    while (n > LCAP){
        float betaRef = __uint_as_float((u32)(key >> 32));
        if (!(betaRef >= T_B_F)) break;
        u32 refIdx = 0xFFFFFFFFu - (u32)(key & 0xFFFFFFFFu);
        if (tid == 0){
            if (snc < CONDCAP) condL[snc] = (int)refIdx;
            snc++;
            size_t rbase = ((size_t)e * P + refIdx) * NF;
            srefc[0] = x[rbase + CCOL];
            srefc[1] = x[rbase + CCOL + 1];
            srefc[2] = x[rbase + CCOL + 2];
            scnt = 0;
        }
        __syncthreads();
        float rx = srefc[0], ry = srefc[1], rz = srefc[2];
        u64 localKey = 0;
        for (int i = tid; i < n; i += FT){
            float4 cc = cIn[i]; int idx = iIn[i];
            float d2 = dist2(cc.x, cc.y, cc.z, rx, ry, rz);
            bool keep = !(d2 <= R2_F);
            u64 bal = __ballot(keep);
            int cw = __popcll(bal);
            int b_ = 0;
            if (lid == 0) b_ = cw ? atomicAdd(&scnt, cw) : 0;
            b_ = __shfl(b_, 0, 64);
            if (keep){
                int pos = b_ + __popcll(bal & ((1ull << lid) - 1));
                cOut[pos] = cc; iOut[pos] = idx;
                localKey = kmax(localKey, makeKey(cc.w, (u32)idx));
            }
        }
        u64 kw = waveReduceMax(localKey);
        if (lid == 0) sred[wid] = kw;
        __syncthreads();
        if (tid == 0){
            u64 m = 0;
            for (int i = 0; i < 16; i++) m = kmax(m, sred[i]);
            skeyb = m;
        }
        __syncthreads();
        key = skeyb; n = scnt;
        { float4* t = cIn; cIn = cOut; cOut = t; }
        { int* t = iIn; iIn = iOut; iOut = t; }
        __syncthreads();
    }

    // ---- phase 2: LDS-resident, single-wave rounds ----
    float betaRef0 = __uint_as_float((u32)(key >> 32));
    if (betaRef0 >= T_B_F && n > 0){
        for (int i = tid; i < n; i += FT){          // stage with all 16 waves
            float4 cc = cIn[i]; int idx = iIn[i];
            skey[i] = makeKey(cc.w, (u32)idx);
            sx[i] = cc.x; sy[i] = cc.y; sz[i] = cc.z;
        }
        __syncthreads();

        if (wid == 0){
            int snc_l = snc;
            int mp = -1;                             // LDS pos of current ref (-1: from global)
            while (true){
                float betaRef = __uint_as_float((u32)(key >> 32));
                if (!(betaRef >= T_B_F)) break;
                u32 refIdx = 0xFFFFFFFFu - (u32)(key & 0xFFFFFFFFu);
                if (lid == 0 && snc_l < CONDCAP) condL[snc_l] = (int)refIdx;
                snc_l++;
                float rx, ry, rz;
                if (mp >= 0){ rx = sx[mp]; ry = sy[mp]; rz = sz[mp]; }
                else {
                    size_t rbase = ((size_t)e * P + refIdx) * NF;
                    rx = x[rbase + CCOL]; ry = x[rbase + CCOL + 1]; rz = x[rbase + CCOL + 2];
                }
                u64 bk = 0; int bp = -1;
                int alive = 0;
                for (int i0 = 0; i0 < n; i0 += 64){
                    int i = i0 + lid;
                    bool inb = i < n;
                    int ii = inb ? i : 0;
                    u64 k = skey[ii];
                    float xx = sx[ii], yy = sy[ii], zz = sz[ii];
                    float d2 = dist2(xx, yy, zz, rx, ry, rz);
                    bool keep = inb && !(d2 <= R2_F);
                    u64 b = __ballot(keep);
                    if (keep){
                        int pos = alive + __popcll(b & ((1ull << lid) - 1));
                        skey[pos] = k; sx[pos] = xx; sy[pos] = yy; sz[pos] = zz;
                        if (k > bk){ bk = k; bp = pos; }
                    }
                    alive += __popcll(b);
                }
                waveReduceMaxPair(bk, bp);
                key = shfl_u64(bk, 0);
                mp = __shfl(bp, 0, 64);
                n = alive;
            }
            if (lid == 0) snc = snc_l;
        }
    }
    __syncthreads();

    // ---- epilogue: scatter condensate rows + row_splits (last block) ----
    int ncT = snc;
    int ncc = ncT > CONDCAP ? CONDCAP : ncT;
    for (int i = tid; i < ncc * NF; i += FT){
        int j = i / NF, f = i - j * NF;
        int row = condL[j];
        size_t base = ((size_t)e * P + row) * NF;
        out[base + f] = x[base + f];
    }
    if (tid == 0){
        ncond[e] = ncT;
        __threadfence();
        int r = atomicAdd(done, 1);
        if (r == E - 1){
            size_t ob = (size_t)E * P * NF;
            int s = 0;
            out[ob] = 0.0f;
            for (int i = 0; i < E; i++){
                s += atomicAdd((int*)&ncond[i], 0);   // device-scope read
                out[ob + i + 1] = (float)s;
            }
        }
    }
}

extern "C" void kernel_launch(void* const* d_in, const int* in_sizes, int n_in,
                              void* d_out, int out_size, void* d_ws, size_t ws_size,
                              hipStream_t stream) {
    const float* x = (const float*)d_in[0];
    int N = in_sizes[0] / NF;
    int E = in_sizes[1] - 1;
    int P = N / E;
    float* out = (float*)d_out;
    char* ws = (char*)d_ws;

    // ws layout (first 4 KB zeroed by k_init)
    u64* argmax1 = (u64*)ws;                        // [E]
    int* cnt0    = (int*)(ws + 1024);               // [E]
    int* cnt1    = (int*)(ws + 1280);               // [E]
    int* candCnt = (int*)(ws + 1536);               // [E]
    int* nrefs   = (int*)(ws + 1792);               // [E]
    int* ncond   = (int*)(ws + 2048);               // [E]
    int* done    = (int*)(ws + 2560);               // [1]
    int* condlist= (int*)(ws + 4096);               // [E][CONDCAP] 16 KB
    float* refXg = (float*)(ws + 20480);            // [E][REFCAP]  16 KB each
    float* refYg = (float*)(ws + 36864);
    float* refZg = (float*)(ws + 53248);
    float4* candC = (float4*)(ws + 69632);          // [E][CANDCAP] float4 = 1.5 MB
    int* candI    = (int*)(ws + 69632 + (size_t)16 * CANDCAP * 16);   // 384 KB
    size_t listOff = 4194304;                       // 4 MB, clear of cand arrays
    size_t listElems = (size_t)E * P;
    float4* cA = (float4*)(ws + listOff);
    float4* cB = (float4*)(ws + listOff + listElems * 16);
    int* iA = (int*)(ws + listOff + listElems * 32);
    int* iB = (int*)(ws + listOff + listElems * 36);

    k_init<<<1, 1024, 0, stream>>>((u32*)ws);

    int chunksPerEvent = P / RPB;                   // 128
    k_filter<<<E * chunksPerEvent, 512, 0, stream>>>(
        (const float4*)x, (float4*)out, cnt0, cA, iA, candCnt, candC, candI,
        P, chunksPerEvent);

    k_resolve<<<E, 1024, 0, stream>>>(
        candC, candI, candCnt, nrefs, condlist, refXg, refYg, refZg);

    int bpe = 32;                                   // 32*256*KB = 65536 = P coverage
    k_kill<<<E * bpe, 256, 0, stream>>>(
        cA, iA, cB, iB, cnt0, cnt1, argmax1, nrefs, refXg, refYg, refZg, P, bpe);

    k_finish2<<<E, 1024, 0, stream>>>(
        x, cB, iB, cA, iA, argmax1, cnt1, nrefs, ncond, condlist, done, out, P, E);
}